// Round 1
// baseline (4673.744 us; speedup 1.0000x reference)
//
#include <hip/hip_runtime.h>
#include <math.h>

namespace {
constexpr int kB = 512;
constexpr int kT = 256;
constexpr int kD = 256;
constexpr int kS = 8;
}

// One block per batch. 256 threads; thread d owns output column d.
// State [S=8][D=256] lives in LDS for the whole time loop.
// Early exit at t == lengths[b] (mask is monotone: state frozen afterwards).
__global__ __launch_bounds__(256, 2)
void dynmem_fp32_kernel(const float* __restrict__ inputs,   // [B, T, D]
                        const int*   __restrict__ lengths,  // [B]
                        const float* __restrict__ keys,     // [S, D]
                        const float* __restrict__ U,        // [D, D]
                        const float* __restrict__ V,        // [D, D]
                        const float* __restrict__ W,        // [D, D]
                        const float* __restrict__ gate_bias,  // [1]
                        const float* __restrict__ state_bias, // [D]
                        float* __restrict__ out)            // [B, S, D]
{
  const int b = blockIdx.x;
  const int d = threadIdx.x;

  __shared__ float Sts[kS][kD];  // current states
  __shared__ float Ks [kS][kD];  // keys (for gate dot)
  __shared__ float KV [kS][kD];  // keys@V + state_bias (loop-invariant)
  __shared__ float xs [kD];      // current x
  __shared__ float red[4][kS];   // per-wave reduction partials
  __shared__ float gsh[kS];      // gates
  __shared__ float inh[kS];      // 1/norm

  // Load keys into LDS; init states = keys.
  for (int i = d; i < kS * kD; i += kD) {
    float kv = keys[i];
    (&Ks[0][0])[i]  = kv;
    (&Sts[0][0])[i] = kv;
  }
  __syncthreads();

  // KV[s][d] = (keys @ V)[s][d] + state_bias[d]   (one-time, ~2K FMAs/thread)
  {
    float acc[kS];
#pragma unroll
    for (int s = 0; s < kS; ++s) acc[s] = 0.f;
    const float* Vc = V + d;
    for (int k = 0; k < kD; ++k) {
      float v = Vc[(size_t)k * kD];
#pragma unroll
      for (int s = 0; s < kS; ++s) acc[s] = fmaf(Ks[s][k], v, acc[s]);
    }
    float sb = state_bias[d];
#pragma unroll
    for (int s = 0; s < kS; ++s) KV[s][d] = acc[s] + sb;
  }

  const float gb = gate_bias[0];
  int len = lengths[b];
  len = len < 0 ? 0 : (len > kT ? kT : len);

  const int lane = d & 63;
  const int wid  = d >> 6;

  const float4* Sts4 = (const float4*)(&Sts[0][0]);
  const float4* xs4  = (const float4*)(&xs[0]);
  const float* Uc = U + d;
  const float* Wc = W + d;

  for (int t = 0; t < len; ++t) {
    float xr = inputs[((size_t)b * kT + t) * kD + d];
    xs[d] = xr;
    __syncthreads();  // B1: xs + prev-step state writes visible

    // ---- gates: g[s] = sigmoid(<x, Sts[s]> + <x, keys[s]> + gb) ----
    float p[kS];
#pragma unroll
    for (int s = 0; s < kS; ++s) p[s] = xr * (Sts[s][d] + Ks[s][d]);
#pragma unroll
    for (int off = 32; off >= 1; off >>= 1) {
#pragma unroll
      for (int s = 0; s < kS; ++s) p[s] += __shfl_xor(p[s], off, 64);
    }
    if (lane == 0) {
#pragma unroll
      for (int s = 0; s < kS; ++s) red[wid][s] = p[s];
    }
    __syncthreads();  // B2: red visible
    if (d < kS) {
      float g = red[0][d] + red[1][d] + red[2][d] + red[3][d] + gb;
      gsh[d] = 1.f / (1.f + expf(-g));
    }

    // ---- matmuls: acc[s] = (Sts @ U)[s][d], accW = (x @ W)[d] ----
    float acc[kS];
#pragma unroll
    for (int s = 0; s < kS; ++s) acc[s] = 0.f;
    float accW = 0.f;
#pragma unroll 2
    for (int k4 = 0; k4 < kD / 4; ++k4) {
      float4 xv = xs4[k4];
      float u0 = Uc[(size_t)(4 * k4 + 0) * kD];
      float u1 = Uc[(size_t)(4 * k4 + 1) * kD];
      float u2 = Uc[(size_t)(4 * k4 + 2) * kD];
      float u3 = Uc[(size_t)(4 * k4 + 3) * kD];
      float w0 = Wc[(size_t)(4 * k4 + 0) * kD];
      float w1 = Wc[(size_t)(4 * k4 + 1) * kD];
      float w2 = Wc[(size_t)(4 * k4 + 2) * kD];
      float w3 = Wc[(size_t)(4 * k4 + 3) * kD];
      accW = fmaf(xv.x, w0, accW);
      accW = fmaf(xv.y, w1, accW);
      accW = fmaf(xv.z, w2, accW);
      accW = fmaf(xv.w, w3, accW);
#pragma unroll
      for (int s = 0; s < kS; ++s) {
        float4 sv = Sts4[s * (kD / 4) + k4];
        acc[s] = fmaf(sv.x, u0, acc[s]);
        acc[s] = fmaf(sv.y, u1, acc[s]);
        acc[s] = fmaf(sv.z, u2, acc[s]);
        acc[s] = fmaf(sv.w, u3, acc[s]);
      }
    }
    __syncthreads();  // B3: gsh visible; all reads of Sts/xs done

    // ---- h = Sts + g*elu(acc + KV + xW); then row-normalize ----
    float hv[kS];
#pragma unroll
    for (int s = 0; s < kS; ++s) {
      float ht = acc[s] + KV[s][d] + accW;
      ht = ht > 0.f ? ht : expm1f(ht);
      float h = fmaf(gsh[s], ht, Sts[s][d]);
      hv[s] = h;
      p[s] = h * h;
    }
#pragma unroll
    for (int off = 32; off >= 1; off >>= 1) {
#pragma unroll
      for (int s = 0; s < kS; ++s) p[s] += __shfl_xor(p[s], off, 64);
    }
    if (lane == 0) {
#pragma unroll
      for (int s = 0; s < kS; ++s) red[wid][s] = p[s];
    }
    __syncthreads();  // B4
    if (d < kS) {
      float nrm = sqrtf(red[0][d] + red[1][d] + red[2][d] + red[3][d]);
      inh[d] = 1.f / fmaxf(nrm, 1e-12f);
    }
    __syncthreads();  // B5: inh visible; red reads done
#pragma unroll
    for (int s = 0; s < kS; ++s) Sts[s][d] = hv[s] * inh[s];
  }

  // Write final states (each thread wrote its own column; no barrier needed).
#pragma unroll
  for (int s = 0; s < kS; ++s)
    out[((size_t)b * kS + s) * kD + d] = Sts[s][d];
}

extern "C" void kernel_launch(void* const* d_in, const int* in_sizes, int n_in,
                              void* d_out, int out_size, void* d_ws, size_t ws_size,
                              hipStream_t stream) {
  const float* inputs     = (const float*)d_in[0];
  const int*   lengths    = (const int*)  d_in[1];
  const float* keys       = (const float*)d_in[2];
  const float* U          = (const float*)d_in[3];
  const float* V          = (const float*)d_in[4];
  const float* W          = (const float*)d_in[5];
  const float* gate_bias  = (const float*)d_in[6];
  const float* state_bias = (const float*)d_in[7];

  dynmem_fp32_kernel<<<dim3(kB), dim3(kD), 0, stream>>>(
      inputs, lengths, keys, U, V, W, gate_bias, state_bias, (float*)d_out);
}

// Round 2
// 4531.494 us; speedup vs baseline: 1.0314x; 1.0314x over previous
//
#include <hip/hip_runtime.h>
#include <math.h>

namespace {
constexpr int kB = 512;
constexpr int kT = 256;
constexpr int kD = 256;
constexpr int kS = 8;
}

// ---------------------------------------------------------------------------
// Kernel A: XW[b,t,:] = inputs[b,t,:] @ W   (M=B*T=131072 rows, K=N=256)
// Block: 32 rows x 256 cols; 256 threads = 4 rowgroups(waves) x 64 colquads.
// Thread computes an 8-row x 4-col microtile.
// ---------------------------------------------------------------------------
__global__ __launch_bounds__(256, 2)
void xw_gemm_kernel(const float* __restrict__ X, const float* __restrict__ W,
                    float* __restrict__ XW) {
  __shared__ float Xs[32][kD];
  const int tid = threadIdx.x;
  const int j  = tid & 63;   // colquad: cols 4j..4j+3
  const int rg = tid >> 6;   // rowgroup: rows rg*8..rg*8+7 (== wave id)
  const int m0 = blockIdx.x * 32;

  const float4* Xg4 = (const float4*)(X + (size_t)m0 * kD);
  float4* Xs4 = (float4*)&Xs[0][0];
  for (int i = tid; i < 32 * kD / 4; i += 256) Xs4[i] = Xg4[i];
  __syncthreads();

  float4 acc[8];
#pragma unroll
  for (int i = 0; i < 8; ++i) acc[i] = make_float4(0.f, 0.f, 0.f, 0.f);

  const float4* W4 = (const float4*)W;
  const float4* Xrow = (const float4*)&Xs[rg * 8][0];

  for (int k4 = 0; k4 < kD / 4; ++k4) {
    float4 w0 = W4[(size_t)(4 * k4 + 0) * 64 + j];
    float4 w1 = W4[(size_t)(4 * k4 + 1) * 64 + j];
    float4 w2 = W4[(size_t)(4 * k4 + 2) * 64 + j];
    float4 w3 = W4[(size_t)(4 * k4 + 3) * 64 + j];
#pragma unroll
    for (int i = 0; i < 8; ++i) {
      float4 x = Xrow[i * 64 + k4];  // LDS broadcast within wave
      acc[i].x = fmaf(x.x, w0.x, fmaf(x.y, w1.x, fmaf(x.z, w2.x, fmaf(x.w, w3.x, acc[i].x))));
      acc[i].y = fmaf(x.x, w0.y, fmaf(x.y, w1.y, fmaf(x.z, w2.y, fmaf(x.w, w3.y, acc[i].y))));
      acc[i].z = fmaf(x.x, w0.z, fmaf(x.y, w1.z, fmaf(x.z, w2.z, fmaf(x.w, w3.z, acc[i].z))));
      acc[i].w = fmaf(x.x, w0.w, fmaf(x.y, w1.w, fmaf(x.z, w2.w, fmaf(x.w, w3.w, acc[i].w))));
    }
  }
  float4* XW4 = (float4*)XW;
#pragma unroll
  for (int i = 0; i < 8; ++i)
    XW4[(size_t)(m0 + rg * 8 + i) * 64 + j] = acc[i];
}

// ---------------------------------------------------------------------------
// Kernel B: GK[b,t,s] = inputs[b,t,:] . keys[s,:]
// One block per batch; each wave handles t = wid, wid+4, ...
// ---------------------------------------------------------------------------
__global__ __launch_bounds__(256, 4)
void gk_kernel(const float* __restrict__ inputs, const float* __restrict__ keys,
               float* __restrict__ GK) {
  const int b = blockIdx.x;
  const int tid = threadIdx.x;
  const int lane = tid & 63;
  const int wid = tid >> 6;

  __shared__ float4 Ks4[kS * 64];
  for (int i = tid; i < kS * 64; i += 256) Ks4[i] = ((const float4*)keys)[i];
  __syncthreads();

  const float4* X4 = (const float4*)inputs;
  for (int t = wid; t < kT; t += 4) {
    float4 x = X4[((size_t)b * kT + t) * 64 + lane];
    float p[kS];
#pragma unroll
    for (int s = 0; s < kS; ++s) {
      float4 kk = Ks4[s * 64 + lane];
      p[s] = fmaf(x.x, kk.x, fmaf(x.y, kk.y, fmaf(x.z, kk.z, x.w * kk.w)));
    }
#pragma unroll
    for (int off = 32; off >= 1; off >>= 1) {
#pragma unroll
      for (int s = 0; s < kS; ++s) p[s] += __shfl_xor(p[s], off, 64);
    }
    if (lane == 0) {
      float* g = GK + ((size_t)b * kT + t) * kS;
#pragma unroll
      for (int s = 0; s < kS; ++s) g[s] = p[s];
    }
  }
}

// ---------------------------------------------------------------------------
// Kernel C: the recurrence. Batch pair (blk, blk+256) in one 512-thread block;
// half h = tid>>8 owns batch b = blk + h*256, thread d = tid&255 owns column d.
// States in LDS; U streamed from L2 (second half L1-hits the first half's rows).
// HOIST=true: x@W and x.keys precomputed (XW, GK). HOIST=false: in-loop.
// ---------------------------------------------------------------------------
template <bool HOIST>
__global__ __launch_bounds__(512, 2)
void dynmem_rec_kernel(const float* __restrict__ inputs,   // [B,T,D]
                       const int*   __restrict__ lengths,  // [B]
                       const float* __restrict__ keys,     // [S,D]
                       const float* __restrict__ U,        // [D,D]
                       const float* __restrict__ V,        // [D,D]
                       const float* __restrict__ W,        // [D,D]
                       const float* __restrict__ gate_bias,
                       const float* __restrict__ state_bias,
                       const float* __restrict__ XW,       // [B,T,D] (HOIST)
                       const float* __restrict__ GK,       // [B,T,S] (HOIST)
                       float* __restrict__ out)            // [B,S,D]
{
  const int blk = blockIdx.x;
  const int tid = threadIdx.x;
  const int h = tid >> 8;
  const int d = tid & 255;
  const int b = blk + (h << 8);

  __shared__ float Sts[2][kS][kD];
  __shared__ float KV[kS][kD];
  __shared__ float Ks[kS][kD];
  __shared__ float xsh[2][kD];   // fallback only
  __shared__ float red[2][4][kS];
  __shared__ float gsh[2][kS];
  __shared__ float inh[2][kS];

  // init: keys -> Ks, states(both halves) = keys
  float* Ksf = &Ks[0][0];
  for (int i = tid; i < kS * kD; i += 512) {
    float v = keys[i];
    Ksf[i] = v;
    (&Sts[0][0][0])[i] = v;
    (&Sts[1][0][0])[i] = v;
  }
  __syncthreads();

  // KV = keys @ V + state_bias (redundant across halves; h==0 writes)
  {
    float acc[kS];
#pragma unroll
    for (int s = 0; s < kS; ++s) acc[s] = 0.f;
    const float* Vc = V + d;
    for (int k = 0; k < kD; ++k) {
      float v = Vc[(size_t)k * kD];
#pragma unroll
      for (int s = 0; s < kS; ++s) acc[s] = fmaf(Ks[s][k], v, acc[s]);
    }
    if (h == 0) {
      float sb = state_bias[d];
#pragma unroll
      for (int s = 0; s < kS; ++s) KV[s][d] = acc[s] + sb;
    }
  }

  const float gb = gate_bias[0];
  int len0 = lengths[blk];       len0 = len0 < 0 ? 0 : (len0 > kT ? kT : len0);
  int len1 = lengths[blk + 256]; len1 = len1 < 0 ? 0 : (len1 > kT ? kT : len1);
  const int mylen = h ? len1 : len0;
  const int tmax = len0 > len1 ? len0 : len1;

  const int lane = tid & 63;
  const int w4 = (tid >> 6) & 3;

  const float4* Sts4 = (const float4*)&Sts[h][0][0];
  const float4* xs4 = (const float4*)&xsh[h][0];
  const float* Uc = U + d;
  const float* Wc = W + d;

  for (int t = 0; t < tmax; ++t) {
    const bool active = t < mylen;
    float xr = 0.f, xw = 0.f;
    if (active) {
      xr = inputs[((size_t)b * kT + t) * kD + d];
      if (HOIST) xw = XW[((size_t)b * kT + t) * kD + d];
    }
    if (!HOIST) xsh[h][d] = xr;
    __syncthreads();  // B1: prev state writes (+xsh) visible

    float p[kS];
    if (active) {
      // gate partials: x . state (+ x . key in fallback)
#pragma unroll
      for (int s = 0; s < kS; ++s)
        p[s] = HOIST ? xr * Sts[h][s][d] : xr * (Sts[h][s][d] + Ks[s][d]);
#pragma unroll
      for (int off = 32; off >= 1; off >>= 1) {
#pragma unroll
        for (int s = 0; s < kS; ++s) p[s] += __shfl_xor(p[s], off, 64);
      }
      if (lane == 0) {
#pragma unroll
        for (int s = 0; s < kS; ++s) red[h][w4][s] = p[s];
      }
    }
    __syncthreads();  // B2: red visible
    if (active && d < kS) {
      float g = red[h][0][d] + red[h][1][d] + red[h][2][d] + red[h][3][d] + gb;
      if (HOIST) g += GK[((size_t)b * kT + t) * kS + d];
      gsh[h][d] = 1.f / (1.f + expf(-g));
    }

    // matmul: acc[s] = (Sts @ U)[s][d] (+ accW = (x@W)[d] in fallback)
    float acc[kS];
#pragma unroll
    for (int s = 0; s < kS; ++s) acc[s] = 0.f;
    float accW = 0.f;
    if (active) {
#pragma unroll 2
      for (int k4 = 0; k4 < kD / 4; ++k4) {
        float u0 = Uc[(size_t)(4 * k4 + 0) * kD];
        float u1 = Uc[(size_t)(4 * k4 + 1) * kD];
        float u2 = Uc[(size_t)(4 * k4 + 2) * kD];
        float u3 = Uc[(size_t)(4 * k4 + 3) * kD];
        if (!HOIST) {
          float4 xv = xs4[k4];
          float w0 = Wc[(size_t)(4 * k4 + 0) * kD];
          float w1 = Wc[(size_t)(4 * k4 + 1) * kD];
          float w2 = Wc[(size_t)(4 * k4 + 2) * kD];
          float w3 = Wc[(size_t)(4 * k4 + 3) * kD];
          accW = fmaf(xv.x, w0, accW);
          accW = fmaf(xv.y, w1, accW);
          accW = fmaf(xv.z, w2, accW);
          accW = fmaf(xv.w, w3, accW);
        }
#pragma unroll
        for (int s = 0; s < kS; ++s) {
          float4 sv = Sts4[s * (kD / 4) + k4];
          acc[s] = fmaf(sv.x, u0, acc[s]);
          acc[s] = fmaf(sv.y, u1, acc[s]);
          acc[s] = fmaf(sv.z, u2, acc[s]);
          acc[s] = fmaf(sv.w, u3, acc[s]);
        }
      }
    }
    __syncthreads();  // B3: gsh visible; state reads done

    float hv[kS];
    if (active) {
#pragma unroll
      for (int s = 0; s < kS; ++s) {
        float ht = acc[s] + KV[s][d] + (HOIST ? xw : accW);
        ht = ht > 0.f ? ht : expm1f(ht);
        float hh = fmaf(gsh[h][s], ht, Sts[h][s][d]);
        hv[s] = hh;
        p[s] = hh * hh;
      }
#pragma unroll
      for (int off = 32; off >= 1; off >>= 1) {
#pragma unroll
        for (int s = 0; s < kS; ++s) p[s] += __shfl_xor(p[s], off, 64);
      }
      if (lane == 0) {
#pragma unroll
        for (int s = 0; s < kS; ++s) red[h][w4][s] = p[s];
      }
    }
    __syncthreads();  // B4
    if (active && d < kS) {
      float n = sqrtf(red[h][0][d] + red[h][1][d] + red[h][2][d] + red[h][3][d]);
      inh[h][d] = 1.f / fmaxf(n, 1e-12f);
    }
    __syncthreads();  // B5: inh visible; red reads done
    if (active) {
#pragma unroll
      for (int s = 0; s < kS; ++s) Sts[h][s][d] = hv[s] * inh[h][s];
    }
  }

#pragma unroll
  for (int s = 0; s < kS; ++s)
    out[((size_t)b * kS + s) * kD + d] = Sts[h][s][d];
}

extern "C" void kernel_launch(void* const* d_in, const int* in_sizes, int n_in,
                              void* d_out, int out_size, void* d_ws, size_t ws_size,
                              hipStream_t stream) {
  const float* inputs     = (const float*)d_in[0];
  const int*   lengths    = (const int*)  d_in[1];
  const float* keys       = (const float*)d_in[2];
  const float* U          = (const float*)d_in[3];
  const float* V          = (const float*)d_in[4];
  const float* W          = (const float*)d_in[5];
  const float* gate_bias  = (const float*)d_in[6];
  const float* state_bias = (const float*)d_in[7];

  const size_t xw_elems = (size_t)kB * kT * kD;          // 33.55M floats
  const size_t gk_elems = (size_t)kB * kT * kS;          // 1.05M floats
  const size_t need = (xw_elems + gk_elems) * sizeof(float);

  if (ws_size >= need) {
    float* XW = (float*)d_ws;
    float* GK = (float*)d_ws + xw_elems;
    xw_gemm_kernel<<<dim3((kB * kT) / 32), dim3(256), 0, stream>>>(inputs, W, XW);
    gk_kernel<<<dim3(kB), dim3(256), 0, stream>>>(inputs, keys, GK);
    dynmem_rec_kernel<true><<<dim3(kB / 2), dim3(512), 0, stream>>>(
        inputs, lengths, keys, U, V, W, gate_bias, state_bias, XW, GK,
        (float*)d_out);
  } else {
    dynmem_rec_kernel<false><<<dim3(kB / 2), dim3(512), 0, stream>>>(
        inputs, lengths, keys, U, V, W, gate_bias, state_bias, nullptr, nullptr,
        (float*)d_out);
  }
}